// Round 11
// baseline (140.713 us; speedup 1.0000x reference)
//
#include <hip/hip_runtime.h>
#include <stdint.h>

#define D_K 512
#define C_CLS 85742
#define N_PART 1340            // ceil(85742/64) — one partial per (row, 64-col)

using bf16x8 = __attribute__((ext_vector_type(8))) short;
using f32x4  = __attribute__((ext_vector_type(4))) float;

// v_cvt_pk_bf16_f32: dst = {lo: bf16(a), hi: bf16(b)}, RNE. No builtin on
// gfx950 (m240) -> inline asm, non-volatile so the scheduler can move it.
__device__ __forceinline__ unsigned int cvtpk(float a, float b) {
  unsigned int r;
  asm("v_cvt_pk_bf16_f32 %0, %1, %2" : "=v"(r) : "v"(a), "v"(b));
  return r;
}
__device__ __forceinline__ unsigned short f2bf(float f) {
  unsigned int u = __builtin_bit_cast(unsigned int, f);
  u += 0x7FFFu + ((u >> 16) & 1u);          // round-to-nearest-even
  return (unsigned short)(u >> 16);
}
__device__ __forceinline__ float bf2f(unsigned short h) {
  return __builtin_bit_cast(float, ((unsigned int)h) << 16);
}
__device__ __forceinline__ float sq8(const float4& a, const float4& b) {
  return a.x*a.x + a.y*a.y + a.z*a.z + a.w*a.w +
         b.x*b.x + b.y*b.y + b.z*b.z + b.w*b.w;
}

#define GLDS(srcp, dstp) __builtin_amdgcn_global_load_lds( \
    (const __attribute__((address_space(1))) unsigned int*)(srcp), \
    (__attribute__((address_space(3))) unsigned int*)(dstp), 16, 0, 0)

// ---------------- Pass A: normalize x -> bf16 xn, save ||x|| ----------------
__global__ __launch_bounds__(256) void k_xnorm(const float* __restrict__ X,
                                               unsigned short* __restrict__ XN,
                                               float* __restrict__ FN) {
  int row  = blockIdx.x * 4 + (threadIdx.x >> 6);
  int lane = threadIdx.x & 63;
  const float4* px = (const float4*)(X + (size_t)row * D_K + lane * 8);
  float4 u = px[0], v = px[1];
  float nsq = sq8(u, v);
#pragma unroll
  for (int m = 1; m <= 32; m <<= 1) nsq += __shfl_xor(nsq, m);
  float nrm = sqrtf(nsq);
  float inv = 1.0f / fmaxf(nrm, 1e-12f);
  uint4 o;
  o.x = cvtpk(u.x*inv, u.y*inv); o.y = cvtpk(u.z*inv, u.w*inv);
  o.z = cvtpk(v.x*inv, v.y*inv); o.w = cvtpk(v.z*inv, v.w*inv);
  *(uint4*)(XN + (size_t)row * D_K + lane * 8) = o;
  if (lane == 0) FN[row] = nrm;
}

// ---- Pass C: FULL-M 512x64 MFMA block — W fp32 read ONCE device-wide and
// ---- converted ONCE. 1024 thr / 16 waves, wave-tile 32x64 (acc[2][4]=32),
// ---- BK=32, 16 K-steps, dbuf LDS, counted vmcnt(1) barrier.
// ---- Per thread-step: 2 A-glds (XN bf16, XOR-swizzled source + swizzled
// ---- read -> conflict-free) + 1 float2 W-load (2-deep) + 1 cvt_pk +
// ---- ds_write to +80B-padded B (conflict-free) + 6 ds_read_b128 + 8 MFMA.
// ---- Fused ||w||^2 from pre-cast f32; epilogue emits (max,sumexp) partials.
__global__ __launch_bounds__(1024, 4) void k_gemm_lse(const float* __restrict__ W,
                                                      const unsigned short* __restrict__ XN,
                                                      const float* __restrict__ FN,
                                                      float2* __restrict__ PART) {
  __shared__ alignas(16) unsigned short As[2][16384];  // [buf][512 rows x 32 cols]
  __shared__ alignas(16) unsigned short Bs[2][2560];   // [buf][64 rows x 40 cols] (+80B pad)
  __shared__ float nsqS[64];

  int bid = blockIdx.x;
  int n0 = bid * 64;

  int t    = threadIdx.x;
  int lane = t & 63, wid = t >> 6;          // 16 waves; wave = rows [wid*32, +32)
  int s = lane & 15, g = lane >> 4;

  // A glds sources (both-sides swizzle, rule 21): instr j covers
  // row r = (wid*2+j)*16 + (lane>>2), stored chunk sc = lane&3; swizzle
  // sc = lc ^ ((r>>1)&3) -> logical chunk lc = (lane&3) ^ ((lane>>3)&3).
  int rA = (lane >> 2);
  int lcA = (lane & 3) ^ ((lane >> 3) & 3);
  const unsigned short* gA0 = XN + (size_t)((wid * 2 + 0) * 16 + rA) * D_K + lcA * 8;
  const unsigned short* gA1 = XN + (size_t)((wid * 2 + 1) * 16 + rA) * D_K + lcA * 8;

  // B source: thread t -> row rB = t>>4, cols (t&15)*2 (+kt*32), float2.
  int rB = t >> 4, cB = t & 15;
  int grB = n0 + rB; if (grB > C_CLS - 1) grB = C_CLS - 1;
  const float* pB = W + (size_t)grB * D_K + cB * 2;

  f32x4 acc[2][4] = {};
  float nsq = 0.f;
  float2 bx, by;

#define STAGE_A(b, kk) do { \
    GLDS(gA0 + (size_t)(kk) * 32, &As[b][(wid * 2 + 0) * 512]); \
    GLDS(gA1 + (size_t)(kk) * 32, &As[b][(wid * 2 + 1) * 512]); \
  } while (0)

#define LDB(kk) (*(const float2*)(pB + (size_t)(kk) * 32))

#define CVTW(bv, b) do { \
    nsq += bv.x * bv.x + bv.y * bv.y; \
    *(unsigned int*)(&Bs[b][rB * 40 + cB * 2]) = cvtpk(bv.x, bv.y); \
  } while (0)

  // A frag: row R = wid*32+mf*16+s, logical chunk g stored at g^((s>>1)&3).
  // B frag: row nf*16+s, padded 80B rows -> conflict-free, aligned.
#define FRAGS_MFMA(b) do { \
    bf16x8 af[2], bfr[4]; \
    _Pragma("unroll") for (int mf = 0; mf < 2; ++mf) { \
      int R_ = wid * 32 + mf * 16 + s; \
      af[mf] = *(const bf16x8*)(&As[b][R_ * 32 + (g ^ ((s >> 1) & 3)) * 8]); \
    } \
    _Pragma("unroll") for (int nf = 0; nf < 4; ++nf) \
      bfr[nf] = *(const bf16x8*)(&Bs[b][(nf * 16 + s) * 40 + g * 8]); \
    _Pragma("unroll") for (int mf = 0; mf < 2; ++mf) \
      _Pragma("unroll") for (int nf = 0; nf < 4; ++nf) \
        acc[mf][nf] = __builtin_amdgcn_mfma_f32_16x16x32_bf16(af[mf], bfr[nf], acc[mf][nf], 0, 0, 0); \
  } while (0)

  // counted barrier: drain the 2 A-glds, keep the newest B-load in flight
#define BARC1() do { \
    asm volatile("s_waitcnt vmcnt(1) lgkmcnt(0)" ::: "memory"); \
    __builtin_amdgcn_s_barrier(); } while (0)
#define BAR0() do { \
    asm volatile("s_waitcnt vmcnt(0) lgkmcnt(0)" ::: "memory"); \
    __builtin_amdgcn_s_barrier(); } while (0)

  // ---- prologue: A(0) + B(0) -> buf0; B(1) stays in flight ----
  STAGE_A(0, 0);                // issue first: oldest in queue
  bx = LDB(0);
  by = LDB(1);
  CVTW(bx, 0);                  // compiler waits bx (drains glds+bx, keeps by)
  BARC1();                      // by in flight across barrier

  // ---- main loop: 7 x 2 K-steps ----
  for (int kt = 0; kt < 14; kt += 2) {
    STAGE_A(1, kt + 1);
    bx = LDB(kt + 2);
    FRAGS_MFMA(0);              // tile kt
    CVTW(by, 1);                // B(kt+1) -> buf1 (loaded last step)
    BARC1();
    STAGE_A(0, kt + 2);
    by = LDB(kt + 3);
    FRAGS_MFMA(1);              // tile kt+1
    CVTW(bx, 0);                // B(kt+2) -> buf0
    BARC1();
  }
  // kt = 14
  STAGE_A(1, 15);
  FRAGS_MFMA(0);
  CVTW(by, 1);                  // B(15)
  BAR0();
  // kt = 15
  FRAGS_MFMA(1);

  // ---- finish ||w||^2: reduce over the 16 col-owners of each row ----
  nsq += __shfl_xor(nsq, 1); nsq += __shfl_xor(nsq, 2);
  nsq += __shfl_xor(nsq, 4); nsq += __shfl_xor(nsq, 8);
  if ((lane & 15) == 0) nsqS[rB] = nsq;
  __syncthreads();

  float rinv[4]; int cvalid[4];
#pragma unroll
  for (int nf = 0; nf < 4; ++nf) {
    cvalid[nf] = (n0 + nf * 16 + s) < C_CLS;
    rinv[nf] = 1.0f / fmaxf(sqrtf(nsqS[nf * 16 + s]), 1e-12f);
  }
  const float NEG_INF = -__builtin_inff();
#pragma unroll
  for (int mf = 0; mf < 2; ++mf) {
#pragma unroll
    for (int q = 0; q < 4; ++q) {
      int rl = wid * 32 + mf * 16 + g * 4 + q;    // D row = (lane>>4)*4+reg
      float fr = FN[rl];
      float z[4]; float mx = NEG_INF;
#pragma unroll
      for (int nf = 0; nf < 4; ++nf) {
        float cc = acc[mf][nf][q] * rinv[nf];
        cc = fminf(fmaxf(cc, -1.0f), 1.0f);
        z[nf] = cvalid[nf] ? cc * fr : NEG_INF;
        mx = fmaxf(mx, z[nf]);
      }
#pragma unroll
      for (int d = 1; d <= 8; d <<= 1) mx = fmaxf(mx, __shfl_xor(mx, d));
      float se = 0.f;
#pragma unroll
      for (int nf = 0; nf < 4; ++nf) se += __expf(z[nf] - mx);  // exp(-inf)=0
#pragma unroll
      for (int d = 1; d <= 8; d <<= 1) se += __shfl_xor(se, d);
      if (s == mf * 4 + q)
        PART[(size_t)rl * N_PART + bid] = make_float2(mx, se);
    }
  }
}

// ------- Pass D: per-row target logit (unmodified + margin-modified) --------
__global__ __launch_bounds__(64) void k_target(const float* __restrict__ W,
                                               const unsigned short* __restrict__ XN,
                                               const float* __restrict__ FN,
                                               const int* __restrict__ LBL,
                                               float2* __restrict__ ZT) {
  int row = blockIdx.x;
  int lane = threadIdx.x;
  int lab = LBL[row];
  const float* pw = W + (size_t)lab * D_K + lane * 8;
  const unsigned short* px = XN + (size_t)row * D_K + lane * 8;
  float dot = 0.f, nsq = 0.f;
#pragma unroll
  for (int j = 0; j < 8; ++j) {
    float w = pw[j];
    nsq += w * w;
    dot += bf2f(px[j]) * bf2f(f2bf(w));   // match GEMM numerics (bf16 operands)
  }
#pragma unroll
  for (int m = 1; m <= 32; m <<= 1) { dot += __shfl_xor(dot, m); nsq += __shfl_xor(nsq, m); }
  if (lane == 0) {
    const float LAMB = 1000.0f / 1.12f;   // iter=1 -> max(5, 1000/1.12)
    float rinv = 1.0f / fmaxf(sqrtf(nsq), 1e-12f);
    float c = fminf(fmaxf(dot * rinv, -1.0f), 1.0f);
    float c2 = c * c;
    float cm = 8.0f * c2 * c2 - 8.0f * c2 + 1.0f;   // cos(4θ)
    float th = acosf(c);
    float kf = floorf(4.0f * th / 3.14159265f);
    float phi = ((((int)kf) & 1) ? -cm : cm) - 2.0f * kf;
    float fr = FN[row];
    float zu = fr * c;
    float zm = fr * (c + (phi - c) / (1.0f + LAMB));
    ZT[row] = make_float2(zu, zm);
  }
}

// ------- Pass E1: combine 1340 partials per row -> per-row CE loss ----------
__global__ __launch_bounds__(256) void k_lse(const float2* __restrict__ PART,
                                             const float2* __restrict__ ZT,
                                             float* __restrict__ LOSSI) {
  int row = blockIdx.x;
  int t = threadIdx.x;
  const float NEG_INF = -__builtin_inff();
  float m = NEG_INF, ss = 0.f;
  for (int p = t; p < N_PART; p += 256) {
    float2 ps = PART[(size_t)row * N_PART + p];
    if (ps.y > 0.f) {
      if (ps.x > m) { ss = ss * __expf(m - ps.x) + ps.y; m = ps.x; }
      else          { ss += ps.y * __expf(ps.x - m); }
    }
  }
  __shared__ float sm[256], sv[256];
  sm[t] = m; sv[t] = ss;
  __syncthreads();
  for (int o = 128; o > 0; o >>= 1) {
    if (t < o) {
      float m1 = sm[t], s1 = sv[t];
      float m2 = sm[t + o], s2 = sv[t + o];
      float mm = fmaxf(m1, m2);
      float e1 = (m1 > NEG_INF) ? s1 * __expf(m1 - mm) : 0.f;
      float e2 = (m2 > NEG_INF) ? s2 * __expf(m2 - mm) : 0.f;
      sm[t] = mm; sv[t] = e1 + e2;
    }
    __syncthreads();
  }
  if (t == 0) {
    float M = sm[0], S = sv[0];
    float2 zt = ZT[row];
    // swap the target's unmodified exp term for the margin-modified one
    S += __expf(zt.y - M) - __expf(zt.x - M);
    LOSSI[row] = M + logf(S) - zt.y;
  }
}

// ------- Pass E2: mean over 512 rows -> scalar loss -------------------------
__global__ __launch_bounds__(256) void k_mean(const float* __restrict__ LOSSI,
                                              float* __restrict__ OUT) {
  int t = threadIdx.x;
  float s_ = LOSSI[t] + LOSSI[t + 256];
#pragma unroll
  for (int m = 1; m <= 32; m <<= 1) s_ += __shfl_xor(s_, m);
  __shared__ float wsum[4];
  if ((t & 63) == 0) wsum[t >> 6] = s_;
  __syncthreads();
  if (t == 0) OUT[0] = (wsum[0] + wsum[1] + wsum[2] + wsum[3]) * (1.0f / 512.0f);
}

extern "C" void kernel_launch(void* const* d_in, const int* in_sizes, int n_in,
                              void* d_out, int out_size, void* d_ws, size_t ws_size,
                              hipStream_t stream) {
  const float* X   = (const float*)d_in[0];   // [512,512] f32
  const float* W   = (const float*)d_in[1];   // [85742,512] f32
  const int*   LBL = (const int*)d_in[2];     // [512] i32
  float* OUT = (float*)d_out;

  char* ws = (char*)d_ws;
  unsigned short* XN = (unsigned short*)ws;            // 512*512*2       = 524288
  float*  FN    = (float*)(ws + 524288);               // 512*4
  float2* ZT    = (float2*)(ws + 526336);              // 512*8
  float*  LOSSI = (float*)(ws + 530432);               // 512*4
  float2* PART  = (float2*)(ws + 532480);              // 512*1340*8 = 5488640

  k_xnorm  <<<dim3(128),  dim3(256),  0, stream>>>(X, XN, FN);
  k_gemm_lse<<<dim3(1340), dim3(1024), 0, stream>>>(W, XN, FN, PART);
  k_target <<<dim3(512),  dim3(64),   0, stream>>>(W, XN, FN, LBL, ZT);
  k_lse    <<<dim3(512),  dim3(256),  0, stream>>>(PART, ZT, LOSSI);
  k_mean   <<<dim3(1),    dim3(256),  0, stream>>>(LOSSI, OUT);
}

// Round 12
// 107.764 us; speedup vs baseline: 1.3058x; 1.3058x over previous
//
#include <hip/hip_runtime.h>
#include <stdint.h>

#define D_K 512
#define C_CLS 85742
#define N_PART 1340            // ceil(85742/64) — one partial per (row, 64-col)

using bf16x8 = __attribute__((ext_vector_type(8))) short;
using f32x4  = __attribute__((ext_vector_type(4))) float;

// v_cvt_pk_bf16_f32: dst = {lo: bf16(a), hi: bf16(b)}, RNE. No builtin on
// gfx950 (m240) -> inline asm, non-volatile so the scheduler can move it.
__device__ __forceinline__ unsigned int cvtpk(float a, float b) {
  unsigned int r;
  asm("v_cvt_pk_bf16_f32 %0, %1, %2" : "=v"(r) : "v"(a), "v"(b));
  return r;
}
__device__ __forceinline__ unsigned short f2bf(float f) {
  unsigned int u = __builtin_bit_cast(unsigned int, f);
  u += 0x7FFFu + ((u >> 16) & 1u);          // round-to-nearest-even
  return (unsigned short)(u >> 16);
}
__device__ __forceinline__ float bf2f(unsigned short h) {
  return __builtin_bit_cast(float, ((unsigned int)h) << 16);
}
__device__ __forceinline__ float sq8(const float4& a, const float4& b) {
  return a.x*a.x + a.y*a.y + a.z*a.z + a.w*a.w +
         b.x*b.x + b.y*b.y + b.z*b.z + b.w*b.w;
}

#define GLDS(srcp, dstp) __builtin_amdgcn_global_load_lds( \
    (const __attribute__((address_space(1))) unsigned int*)(srcp), \
    (__attribute__((address_space(3))) unsigned int*)(dstp), 16, 0, 0)

// ---------------- Pass A: normalize x -> bf16 xn, save ||x|| ----------------
__global__ __launch_bounds__(256) void k_xnorm(const float* __restrict__ X,
                                               unsigned short* __restrict__ XN,
                                               float* __restrict__ FN) {
  int row  = blockIdx.x * 4 + (threadIdx.x >> 6);
  int lane = threadIdx.x & 63;
  const float4* px = (const float4*)(X + (size_t)row * D_K + lane * 8);
  float4 u = px[0], v = px[1];
  float nsq = sq8(u, v);
#pragma unroll
  for (int m = 1; m <= 32; m <<= 1) nsq += __shfl_xor(nsq, m);
  float nrm = sqrtf(nsq);
  float inv = 1.0f / fmaxf(nrm, 1e-12f);
  uint4 o;
  o.x = cvtpk(u.x*inv, u.y*inv); o.y = cvtpk(u.z*inv, u.w*inv);
  o.z = cvtpk(v.x*inv, v.y*inv); o.w = cvtpk(v.z*inv, v.w*inv);
  *(uint4*)(XN + (size_t)row * D_K + lane * 8) = o;
  if (lane == 0) FN[row] = nrm;
}

// ---- Pass C: FULL-M 512x64 MFMA block at 512 THREADS (8 waves, M-stacked,
// ---- wave-tile 64x64, acc[4][4]) — W fp32 read ONCE and converted ONCE
// ---- device-wide. BK=32, dbuf LDS, ONE counted vmcnt(1) barrier per K-step:
// ---- steady-state VMEM queue = [B(kt+2)] surviving each barrier, A-glds
// ---- drained after a full MFMA phase. A: 4 glds/thread, each wave stages its
// ---- own 64 rows, XOR-swizzled source + swizzled read (conflict-free).
// ---- B: 1 float4 + 2 cvt_pk + ds_write to 80B-padded rows (2-way max).
// ---- Fused ||w||^2; epilogue emits per-(row,64col) (max,sumexp) partials.
__global__ __launch_bounds__(512, 2) void k_gemm_lse(const float* __restrict__ W,
                                                     const unsigned short* __restrict__ XN,
                                                     const float* __restrict__ FN,
                                                     float2* __restrict__ PART) {
  __shared__ alignas(16) unsigned short As[2][16384];  // [buf][512 rows x 32 cols]
  __shared__ alignas(16) unsigned short Bs[2][2560];   // [buf][64 rows x 40 cols]
  __shared__ float nsqS[64];

  int bid = blockIdx.x;
  // bijective XCD chunking for 1340 = 8*167 + 4 (m204 formula)
  int xcd = bid & 7, loc = bid >> 3;
  int nb = (xcd < 4 ? xcd * 168 : 4 * 168 + (xcd - 4) * 167) + loc;
  int n0 = nb * 64;

  int t    = threadIdx.x;
  int lane = t & 63, wid = t >> 6;          // 8 waves; wave owns rows [wid*64,+64)
  int s = lane & 15, g = lane >> 4;

  // A glds sources: instr j covers row r = wid*64 + j*16 + (lane>>2), stored
  // chunk sc = lane&3; logical chunk lc = sc ^ ((r>>1)&3) = sc ^ ((lane>>3)&3).
  int rAl = lane >> 2;
  int lcA = (lane & 3) ^ ((lane >> 3) & 3);
  const unsigned short* gA0 = XN + (size_t)(wid * 64 + rAl) * D_K + lcA * 8;
  const unsigned short* gA1 = gA0 + (size_t)16 * D_K;
  const unsigned short* gA2 = gA0 + (size_t)32 * D_K;
  const unsigned short* gA3 = gA0 + (size_t)48 * D_K;

  // B source: thread t -> row rB = t>>3 (64 rows), f32 cols (t&7)*4 (+kt*32)
  int rB = t >> 3, c8 = t & 7;
  int grB = n0 + rB; if (grB > C_CLS - 1) grB = C_CLS - 1;
  const float* pB = W + (size_t)grB * D_K + c8 * 4;

  f32x4 acc[4][4] = {};
  float nsq = 0.f;
  float4 bx, by;                // 2-deep B prefetch queue

#define STAGE_A(b, kk) do { \
    GLDS(gA0 + (size_t)(kk) * 32, &As[b][wid * 2048 +    0]); \
    GLDS(gA1 + (size_t)(kk) * 32, &As[b][wid * 2048 +  512]); \
    GLDS(gA2 + (size_t)(kk) * 32, &As[b][wid * 2048 + 1024]); \
    GLDS(gA3 + (size_t)(kk) * 32, &As[b][wid * 2048 + 1536]); \
  } while (0)

#define LDB4(kk) (*(const float4*)(pB + (size_t)(kk) * 32))

#define CVTW(bv, b) do { \
    nsq += bv.x * bv.x + bv.y * bv.y + bv.z * bv.z + bv.w * bv.w; \
    uint2 u_ = make_uint2(cvtpk(bv.x, bv.y), cvtpk(bv.z, bv.w)); \
    *(uint2*)(&Bs[b][rB * 40 + c8 * 4]) = u_; \
  } while (0)

  // A frag: row R = wid*64+mf*16+s, logical chunk g stored at g^((s>>1)&3).
  // B frag: row nf*16+s, 80B-padded rows -> ~2-way max, 16B-aligned.
#define FRAGS_MFMA(b) do { \
    bf16x8 af[4], bfr[4]; \
    _Pragma("unroll") for (int mf = 0; mf < 4; ++mf) \
      af[mf] = *(const bf16x8*)(&As[b][(wid * 64 + mf * 16 + s) * 32 + (g ^ ((s >> 1) & 3)) * 8]); \
    _Pragma("unroll") for (int nf = 0; nf < 4; ++nf) \
      bfr[nf] = *(const bf16x8*)(&Bs[b][(nf * 16 + s) * 40 + g * 8]); \
    _Pragma("unroll") for (int mf = 0; mf < 4; ++mf) \
      _Pragma("unroll") for (int nf = 0; nf < 4; ++nf) \
        acc[mf][nf] = __builtin_amdgcn_mfma_f32_16x16x32_bf16(af[mf], bfr[nf], acc[mf][nf], 0, 0, 0); \
  } while (0)

#define BARC1() do { \
    asm volatile("s_waitcnt vmcnt(1) lgkmcnt(0)" ::: "memory"); \
    __builtin_amdgcn_s_barrier(); } while (0)
#define BAR0() do { \
    asm volatile("s_waitcnt vmcnt(0) lgkmcnt(0)" ::: "memory"); \
    __builtin_amdgcn_s_barrier(); } while (0)

  // ---- prologue: tile 0 -> buf0; B(1) survives the barrier ----
  STAGE_A(0, 0);
  bx = LDB4(0);
  by = LDB4(1);
  CVTW(bx, 0);                  // waits bx -> also drains the older 4 glds
  BARC1();                      // queue [by]; buf0 published

  // ---- main loop: 7 iters x 2 K-steps, one vmcnt(1) barrier each ----
  for (int kt = 0; kt < 14; kt += 2) {
    STAGE_A(1, kt + 1);         // 4 glds -> buf1
    bx = LDB4(kt + 2);
    FRAGS_MFMA(0);              // tile kt (covers the loads above)
    CVTW(by, 1);                // B(kt+1) -> buf1 (waits by only)
    BARC1();                    // drains the 4 glds; bx survives
    STAGE_A(0, kt + 2);
    by = LDB4(kt + 3);
    FRAGS_MFMA(1);              // tile kt+1
    CVTW(bx, 0);                // B(kt+2) -> buf0
    BARC1();                    // drains glds; by survives
  }
  // tail: queue [by = B(15)]; buf0 holds tile 14
  STAGE_A(1, 15);
  FRAGS_MFMA(0);                // tile 14
  CVTW(by, 1);                  // B(15) (waits by; glds still flying)
  BAR0();                       // drain A(15)
  FRAGS_MFMA(1);                // tile 15

  // ---- finish ||w||^2: reduce over the 8 col-owners of each row ----
  nsq += __shfl_xor(nsq, 1); nsq += __shfl_xor(nsq, 2); nsq += __shfl_xor(nsq, 4);
  if (c8 == 0) nsqS[rB] = nsq;
  __syncthreads();

  float rinv[4]; int cvalid[4];
#pragma unroll
  for (int nf = 0; nf < 4; ++nf) {
    cvalid[nf] = (n0 + nf * 16 + s) < C_CLS;
    rinv[nf] = 1.0f / fmaxf(sqrtf(nsqS[nf * 16 + s]), 1e-12f);
  }
  const float NEG_INF = -__builtin_inff();
#pragma unroll
  for (int mf = 0; mf < 4; ++mf) {
#pragma unroll
    for (int q = 0; q < 4; ++q) {
      int rl = wid * 64 + mf * 16 + g * 4 + q;    // D row = (lane>>4)*4+reg
      float fr = FN[rl];
      float z[4]; float mx = NEG_INF;
#pragma unroll
      for (int nf = 0; nf < 4; ++nf) {
        float cc = acc[mf][nf][q] * rinv[nf];
        cc = fminf(fmaxf(cc, -1.0f), 1.0f);
        z[nf] = cvalid[nf] ? cc * fr : NEG_INF;
        mx = fmaxf(mx, z[nf]);
      }
#pragma unroll
      for (int d = 1; d <= 8; d <<= 1) mx = fmaxf(mx, __shfl_xor(mx, d));
      float se = 0.f;
#pragma unroll
      for (int nf = 0; nf < 4; ++nf) se += __expf(z[nf] - mx);  // exp(-inf)=0
#pragma unroll
      for (int d = 1; d <= 8; d <<= 1) se += __shfl_xor(se, d);
      if (s == mf * 4 + q)
        PART[(size_t)rl * N_PART + nb] = make_float2(mx, se);
    }
  }
}

// ------- Pass D: per-row target logit (unmodified + margin-modified) --------
__global__ __launch_bounds__(64) void k_target(const float* __restrict__ W,
                                               const unsigned short* __restrict__ XN,
                                               const float* __restrict__ FN,
                                               const int* __restrict__ LBL,
                                               float2* __restrict__ ZT) {
  int row = blockIdx.x;
  int lane = threadIdx.x;
  int lab = LBL[row];
  const float* pw = W + (size_t)lab * D_K + lane * 8;
  const unsigned short* px = XN + (size_t)row * D_K + lane * 8;
  float dot = 0.f, nsq = 0.f;
#pragma unroll
  for (int j = 0; j < 8; ++j) {
    float w = pw[j];
    nsq += w * w;
    dot += bf2f(px[j]) * bf2f(f2bf(w));   // match GEMM numerics (bf16 operands)
  }
#pragma unroll
  for (int m = 1; m <= 32; m <<= 1) { dot += __shfl_xor(dot, m); nsq += __shfl_xor(nsq, m); }
  if (lane == 0) {
    const float LAMB = 1000.0f / 1.12f;   // iter=1 -> max(5, 1000/1.12)
    float rinv = 1.0f / fmaxf(sqrtf(nsq), 1e-12f);
    float c = fminf(fmaxf(dot * rinv, -1.0f), 1.0f);
    float c2 = c * c;
    float cm = 8.0f * c2 * c2 - 8.0f * c2 + 1.0f;   // cos(4θ)
    float th = acosf(c);
    float kf = floorf(4.0f * th / 3.14159265f);
    float phi = ((((int)kf) & 1) ? -cm : cm) - 2.0f * kf;
    float fr = FN[row];
    float zu = fr * c;
    float zm = fr * (c + (phi - c) / (1.0f + LAMB));
    ZT[row] = make_float2(zu, zm);
  }
}

// ------- Pass E1: combine 1340 partials per row -> per-row CE loss ----------
__global__ __launch_bounds__(256) void k_lse(const float2* __restrict__ PART,
                                             const float2* __restrict__ ZT,
                                             float* __restrict__ LOSSI) {
  int row = blockIdx.x;
  int t = threadIdx.x;
  const float NEG_INF = -__builtin_inff();
  float m = NEG_INF, ss = 0.f;
  for (int p = t; p < N_PART; p += 256) {
    float2 ps = PART[(size_t)row * N_PART + p];
    if (ps.y > 0.f) {
      if (ps.x > m) { ss = ss * __expf(m - ps.x) + ps.y; m = ps.x; }
      else          { ss += ps.y * __expf(ps.x - m); }
    }
  }
  __shared__ float sm[256], sv[256];
  sm[t] = m; sv[t] = ss;
  __syncthreads();
  for (int o = 128; o > 0; o >>= 1) {
    if (t < o) {
      float m1 = sm[t], s1 = sv[t];
      float m2 = sm[t + o], s2 = sv[t + o];
      float mm = fmaxf(m1, m2);
      float e1 = (m1 > NEG_INF) ? s1 * __expf(m1 - mm) : 0.f;
      float e2 = (m2 > NEG_INF) ? s2 * __expf(m2 - mm) : 0.f;
      sm[t] = mm; sv[t] = e1 + e2;
    }
    __syncthreads();
  }
  if (t == 0) {
    float M = sm[0], S = sv[0];
    float2 zt = ZT[row];
    // swap the target's unmodified exp term for the margin-modified one
    S += __expf(zt.y - M) - __expf(zt.x - M);
    LOSSI[row] = M + logf(S) - zt.y;
  }
}

// ------- Pass E2: mean over 512 rows -> scalar loss -------------------------
__global__ __launch_bounds__(256) void k_mean(const float* __restrict__ LOSSI,
                                              float* __restrict__ OUT) {
  int t = threadIdx.x;
  float s_ = LOSSI[t] + LOSSI[t + 256];
#pragma unroll
  for (int m = 1; m <= 32; m <<= 1) s_ += __shfl_xor(s_, m);
  __shared__ float wsum[4];
  if ((t & 63) == 0) wsum[t >> 6] = s_;
  __syncthreads();
  if (t == 0) OUT[0] = (wsum[0] + wsum[1] + wsum[2] + wsum[3]) * (1.0f / 512.0f);
}

extern "C" void kernel_launch(void* const* d_in, const int* in_sizes, int n_in,
                              void* d_out, int out_size, void* d_ws, size_t ws_size,
                              hipStream_t stream) {
  const float* X   = (const float*)d_in[0];   // [512,512] f32
  const float* W   = (const float*)d_in[1];   // [85742,512] f32
  const int*   LBL = (const int*)d_in[2];     // [512] i32
  float* OUT = (float*)d_out;

  char* ws = (char*)d_ws;
  unsigned short* XN = (unsigned short*)ws;            // 512*512*2       = 524288
  float*  FN    = (float*)(ws + 524288);               // 512*4
  float2* ZT    = (float2*)(ws + 526336);              // 512*8
  float*  LOSSI = (float*)(ws + 530432);               // 512*4
  float2* PART  = (float2*)(ws + 532480);              // 512*1340*8 = 5488640

  k_xnorm  <<<dim3(128),  dim3(256), 0, stream>>>(X, XN, FN);
  k_gemm_lse<<<dim3(1340), dim3(512), 0, stream>>>(W, XN, FN, PART);
  k_target <<<dim3(512),  dim3(64),  0, stream>>>(W, XN, FN, LBL, ZT);
  k_lse    <<<dim3(512),  dim3(256), 0, stream>>>(PART, ZT, LOSSI);
  k_mean   <<<dim3(1),    dim3(256), 0, stream>>>(LOSSI, OUT);
}